// Round 4
// baseline (477.743 us; speedup 1.0000x reference)
//
#include <hip/hip_runtime.h>
#include <hip/hip_bf16.h>
#include <stdint.h>

typedef __attribute__((ext_vector_type(8))) short short8;
typedef __attribute__((ext_vector_type(4))) short short4v;
typedef __attribute__((ext_vector_type(4))) float f32x4;

__device__ inline unsigned short f2bf(float f) {
    union { float f; uint32_t u; } v; v.f = f;
    uint32_t u = v.u;
    uint32_t r = (u + 0x7FFFu + ((u >> 16) & 1u)) >> 16;   // RNE
    return (unsigned short)r;
}

__device__ inline short4v pk4(float4 a) {
    short4v r;
    r[0] = (short)f2bf(a.x); r[1] = (short)f2bf(a.y);
    r[2] = (short)f2bf(a.z); r[3] = (short)f2bf(a.w);
    return r;
}

// ---------------- Router kernel 1: partial GEMM  h_pre = g_in @ W1 -------------
// grid (4 jc, 64 ks), 512 thr. Each thread: 1 j, all 64 batteries (64 f32 accs,
// no spill). DKP accessed with wave-uniform addresses -> compiler emits scalar
// loads (SGPR operand into v_fma); W1 read exactly once, fully coalesced.
__global__ __launch_bounds__(512) void router1(const float* __restrict__ DKP,
                                               const float* __restrict__ W1,
                                               float* __restrict__ part) {
    const int t  = threadIdx.x;
    const int jc = blockIdx.x;       // 0..3
    const int ks = blockIdx.y;       // 0..63
    const int k0 = ks * 64;
    const int j  = jc * 512 + t;
    float acc[64];
    #pragma unroll
    for (int b = 0; b < 64; ++b) acc[b] = 0.f;
    #pragma unroll 1
    for (int oct = 0; oct < 8; ++oct) {
        const int kk = k0 + oct * 8;
        float w[8];
        #pragma unroll
        for (int i = 0; i < 8; ++i)
            w[i] = W1[(size_t)(kk + i) * 2048 + j];
        #pragma unroll
        for (int b = 0; b < 64; ++b) {
            const float* dk = DKP + (size_t)b * 4096 + kk;   // uniform -> s_load
            acc[b] += dk[0]*w[0] + dk[1]*w[1] + dk[2]*w[2] + dk[3]*w[3]
                    + dk[4]*w[4] + dk[5]*w[5] + dk[6]*w[6] + dk[7]*w[7];
        }
    }
    #pragma unroll 1
    for (int b = 0; b < 64; ++b)
        part[(size_t)(ks * 64 + b) * 2048 + j] = acc[b];
}

// ---------------- Router kernel 2: reduce splits + cycle-number col + bias + GELU
__global__ __launch_bounds__(256) void router2(const float* __restrict__ part,
                                               const float* __restrict__ cyc,
                                               const float* __restrict__ W1,
                                               const float* __restrict__ b1,
                                               float* __restrict__ h) {
    const int idx = blockIdx.x * 256 + threadIdx.x;   // idx = b*2048 + j
    const int j = idx & 2047, b = idx >> 11;
    float s = 0.f;
    #pragma unroll 8
    for (int t = 0; t < 64; ++t)
        s += part[((size_t)t * 64 + b) * 2048 + j];
    s += cyc[b] * W1[(size_t)4096 * 2048 + j] + b1[j];
    const float u  = s + 0.044715f * s * s * s;
    const float th = tanhf(0.7978845608028654f * u);
    h[idx] = 0.5f * s * (1.0f + th);
}

// ---------------- Router kernel 3: logits, top-2, softmax, renorm gates -------
__global__ __launch_bounds__(256) void router3(const float* __restrict__ h,
                                               const float* __restrict__ W2,
                                               const float* __restrict__ b2,
                                               float4* __restrict__ gates) {
    __shared__ float red[256 * 8];
    __shared__ float lg[8];
    const int b = blockIdx.x, t = threadIdx.x;
    float acc[8];
    #pragma unroll
    for (int e = 0; e < 8; ++e) acc[e] = 0.f;
    for (int k = t; k < 2048; k += 256) {
        const float hv = h[(size_t)b * 2048 + k];
        const float* w = W2 + (size_t)k * 8;
        #pragma unroll
        for (int e = 0; e < 8; ++e) acc[e] += hv * w[e];
    }
    #pragma unroll
    for (int e = 0; e < 8; ++e) red[t * 8 + e] = acc[e];
    __syncthreads();
    if (t < 8) {
        float s = 0.f;
        for (int r = 0; r < 256; ++r) s += red[r * 8 + t];
        lg[t] = s + b2[t];
    }
    __syncthreads();
    if (t == 0) {
        float l[8];
        #pragma unroll
        for (int e = 0; e < 8; ++e) l[e] = lg[e];
        int e0 = 0;
        #pragma unroll
        for (int e = 1; e < 8; ++e) if (l[e] > l[e0]) e0 = e;
        int e1 = (e0 == 0) ? 1 : 0;
        #pragma unroll
        for (int e = 0; e < 8; ++e) if (e != e0 && l[e] > l[e1]) e1 = e;
        const float m = l[e0];
        float p[8], Z = 0.f;
        #pragma unroll
        for (int e = 0; e < 8; ++e) { p[e] = expf(l[e] - m); Z += p[e]; }
        const float pe0 = p[e0] / Z, pe1 = p[e1] / Z;
        const float s2 = pe0 + pe1 + 1e-9f;
        gates[b] = make_float4(__int_as_float(e0), __int_as_float(e1), pe0 / s2, pe1 / s2);
    }
}

// ---------------- Combine weights -> FRAG-LINEAR layout, bf16, K-pad to 928 ---
// Layout: chunk (b, nb 0..31, kc 0..28) of 512 elems; within a chunk element
// (n = nb*16 + (l&15), k = kc*32 + (l>>4)*8 + j) lives at l*8 + j. A wave's
// MFMA B-fragment is then ONE coalesced global_load_dwordx4 (lane -> lane*16B).
// grid (64 b fast, 29 kc): all batteries of one kc run together -> genW/expW
// k-rows L2-resident across the 64 blocks. Writes fully coalesced (1KB/wave).
__global__ __launch_bounds__(256) void combine_w(const float* __restrict__ genW,
                                                 const float* __restrict__ expW,
                                                 const float4* __restrict__ gates,
                                                 unsigned short* __restrict__ wc) {
    const int b  = blockIdx.x;    // fast dim
    const int kc = blockIdx.y;    // 0..28
    const float4 gt = gates[b];
    const int e0 = __float_as_int(gt.x), e1 = __float_as_int(gt.y);
    const float g0 = gt.z, g1 = gt.w;
    const float* W0  = expW + (size_t)e0 * 900 * 512;
    const float* W1e = expW + (size_t)e1 * 900 * 512;
    const int t = threadIdx.x, l = t & 63, w = t >> 6;
    const int lm = l & 15, lq = l >> 4;
    unsigned short* outb = wc + (size_t)b * 32 * 29 * 512;
    #pragma unroll
    for (int q = 0; q < 8; ++q) {
        const int nb = w * 8 + q;
        const int n  = nb * 16 + lm;
        short8 v;
        #pragma unroll
        for (int j = 0; j < 8; ++j) {
            const int k = kc * 32 + lq * 8 + j;
            float f = 0.f;
            if (k < 900) {
                const size_t o = (size_t)k * 512 + n;
                f = genW[o] + g0 * W0[o] + g1 * W1e[o];
            }
            v[j] = (short)f2bf(f);
        }
        *(short8*)(outb + (size_t)(nb * 29 + kc) * 512 + l * 8) = v;
    }
}

// ---------------- Main fused batched GEMM: out[b] = x[b] @ Wcomb_b + bias ------
// BARRIER-FREE K-loop: A-tile (32 rows x 928k bf16, 58.5KB) resident in LDS
// (staged once, one __syncthreads); B-frags stream from frag-linear Wcomb
// straight into VGPRs (one coalesced dwordx4 per frag, L2-served), register
// double-rotation prefetch distance 2. No per-iter vmcnt(0) drain -> compiler
// emits fine-grained waits; loads overlap MFMA freely. 256 thr / 4 waves, each
// wave 32m x 128n (2x8 frags, 16 MFMA/iter). 2 blocks/CU (LDS-limited).
// grid (64 b, 16 lt): XCD = b%8 -> per-XCD 8 Wcomb streams, 8 sharers each.
__global__ __launch_bounds__(256, 2) void moe_gemm(const float* __restrict__ x,
                                                   const unsigned short* __restrict__ wc,
                                                   const float4* __restrict__ gates,
                                                   const float* __restrict__ eb,
                                                   const float* __restrict__ genb,
                                                   float* __restrict__ out) {
    __shared__ unsigned short As[32 * 936];   // row stride 936: 2-way banks on frag reads
    const int b  = blockIdx.x;
    const int m0 = blockIdx.y * 32;
    const int t = threadIdx.x, lane = t & 63, wid = t >> 6;
    // ---- A stage (once)
    {
        const int r = t >> 3, s = t & 7;
        const float* xrow = x + ((size_t)b * 512 + m0 + r) * 900;
        unsigned short* arow = As + r * 936;
        for (int c = s * 4; c < 900; c += 32)
            *(short4v*)(arow + c) = pk4(*(const float4*)(xrow + c));
        if (s < 7) *(short4v*)(arow + 900 + s * 4) = (short4v){0, 0, 0, 0};
    }
    const float4 gt = gates[b];
    const int e0 = __float_as_int(gt.x), e1 = __float_as_int(gt.y);
    const float g0 = gt.z, g1 = gt.w;
    // ---- B prefetch kt=0,1 (overlaps A stage; complete at the barrier)
    const unsigned short* wcb = wc + (size_t)b * 32 * 29 * 512;
    const unsigned short* bptr[8];
    #pragma unroll
    for (int q = 0; q < 8; ++q)
        bptr[q] = wcb + (size_t)((wid * 8 + q) * 29) * 512 + lane * 8;
    short8 B0[8], B1[8];
    #pragma unroll
    for (int q = 0; q < 8; ++q) B0[q] = *(const short8*)(bptr[q]);
    #pragma unroll
    for (int q = 0; q < 8; ++q) B1[q] = *(const short8*)(bptr[q] + 512);
    __syncthreads();
    // ---- K loop, no barriers
    const int lm = lane & 15, lq = lane >> 4;
    f32x4 acc[2][8];
    #pragma unroll
    for (int mi = 0; mi < 2; ++mi)
        #pragma unroll
        for (int q = 0; q < 8; ++q)
            acc[mi][q] = (f32x4){0.f, 0.f, 0.f, 0.f};

    #pragma unroll 1
    for (int kt = 0; kt < 29; kt += 2) {
        short8 af0, af1;
        af0 = *(const short8*)&As[(lm)      * 936 + kt * 32 + lq * 8];
        af1 = *(const short8*)&As[(16 + lm) * 936 + kt * 32 + lq * 8];
        #pragma unroll
        for (int q = 0; q < 8; ++q) {
            acc[0][q] = __builtin_amdgcn_mfma_f32_16x16x32_bf16(af0, B0[q], acc[0][q], 0, 0, 0);
            acc[1][q] = __builtin_amdgcn_mfma_f32_16x16x32_bf16(af1, B0[q], acc[1][q], 0, 0, 0);
        }
        if (kt + 2 < 29) {
            #pragma unroll
            for (int q = 0; q < 8; ++q)
                B0[q] = *(const short8*)(bptr[q] + (size_t)(kt + 2) * 512);
        }
        if (kt + 1 < 29) {
            af0 = *(const short8*)&As[(lm)      * 936 + (kt + 1) * 32 + lq * 8];
            af1 = *(const short8*)&As[(16 + lm) * 936 + (kt + 1) * 32 + lq * 8];
            #pragma unroll
            for (int q = 0; q < 8; ++q) {
                acc[0][q] = __builtin_amdgcn_mfma_f32_16x16x32_bf16(af0, B1[q], acc[0][q], 0, 0, 0);
                acc[1][q] = __builtin_amdgcn_mfma_f32_16x16x32_bf16(af1, B1[q], acc[1][q], 0, 0, 0);
            }
            if (kt + 3 < 29) {
                #pragma unroll
                for (int q = 0; q < 8; ++q)
                    B1[q] = *(const short8*)(bptr[q] + (size_t)(kt + 3) * 512);
            }
        }
    }
    // ---- Epilogue: bias + store f32
    #pragma unroll
    for (int q = 0; q < 8; ++q) {
        const int col = wid * 128 + q * 16 + lm;
        const float bias = genb[col] + g0 * eb[e0 * 512 + col] + g1 * eb[e1 * 512 + col];
        #pragma unroll
        for (int mi = 0; mi < 2; ++mi) {
            const int row = m0 + mi * 16 + lq * 4;
            #pragma unroll
            for (int r = 0; r < 4; ++r)
                out[((size_t)b * 512 + row + r) * 512 + col] = acc[mi][q][r] + bias;
        }
    }
}

extern "C" void kernel_launch(void* const* d_in, const int* in_sizes, int n_in,
                              void* d_out, int out_size, void* d_ws, size_t ws_size,
                              hipStream_t stream) {
    const float* x    = (const float*)d_in[0];   // [64][512][900]
    const float* cyc  = (const float*)d_in[1];   // [64][1]
    const float* dkp  = (const float*)d_in[2];   // [64][4096]
    const float* gW1  = (const float*)d_in[3];   // [4097][2048]
    const float* gb1  = (const float*)d_in[4];   // [2048]
    const float* gW2  = (const float*)d_in[5];   // [2048][8]
    const float* gb2  = (const float*)d_in[6];   // [8]
    const float* eW   = (const float*)d_in[7];   // [8][900][512]
    const float* eb   = (const float*)d_in[8];   // [8][512]
    const float* genW = (const float*)d_in[9];   // [900][512]
    const float* genb = (const float*)d_in[10];  // [512]
    float* out = (float*)d_out;                  // [64][512][512] f32

    char* ws = (char*)d_ws;
    // ws: [0, 60817408) Wcomb frag-linear bf16 [64][32 nb][29 kc][512];
    // partials (33.5MB, [64 ks][64 b][2048 j] f32) alias it (dead before
    // combine_w). Then h (512KB), gates (1KB).
    unsigned short* wcomb = (unsigned short*)ws;
    float* part  = (float*)ws;
    float* h     = (float*)(ws + 60817408);
    float4* gts  = (float4*)(ws + 60817408 + 524288);

    router1<<<dim3(4, 64), 512, 0, stream>>>(dkp, gW1, part);
    router2<<<512, 256, 0, stream>>>(part, cyc, gW1, gb1, h);
    router3<<<64, 256, 0, stream>>>(h, gW2, gb2, gts);
    combine_w<<<dim3(64, 29), 256, 0, stream>>>(genW, eW, gts, wcomb);
    moe_gemm<<<dim3(64, 16), 256, 0, stream>>>(x, wcomb, gts, eb, genb, out);
}